// Round 2
// baseline (82.683 us; speedup 1.0000x reference)
//
#include <hip/hip_runtime.h>
#include <stdint.h>
#include <math.h>

// SamplePatches: gumbel top-k sampling (Threefry2x32 counter-mode, key 42) + patch gather.
// Inputs: d_in[0]=x_low (unused), d_in[1]=x_high (unused),
//         d_in[2]=attention [4,64,64] f32, d_in[3]=WSI [4,3,2048,2048] f32.
// Output: patches [4,32,3,128,128] f32 then sampled_attention [4,32] f32, concat flat.
//
// NOTE: modern JAX defaults jax_threefry_partitionable=True, so random bits for
// element e are threefry2x32(key, (hi=0, lo=e)) with the two output words XOR-folded.

namespace {
constexpr int B      = 4;
constexpr int NP     = 32;     // N_PATCHES
constexpr int PATCH_ = 128;
constexpr int GRID   = 4096;   // 64*64 attention cells per batch
constexpr int HW     = 2048;
constexpr float EPSF = 1e-12f;

__device__ inline uint32_t rotl32(uint32_t x, uint32_t r){ return (x<<r)|(x>>(32u-r)); }

// Threefry-2x32 with key (0, 42)  == jax.random.key(42)
__device__ inline void threefry2x32_k042(uint32_t x0, uint32_t x1,
                                         uint32_t& o0, uint32_t& o1){
  const uint32_t k0 = 0u, k1 = 42u;
  const uint32_t k2 = k0 ^ k1 ^ 0x1BD11BDAu;
  x0 += k0; x1 += k1;
#define RND(r) { x0 += x1; x1 = rotl32(x1,(r)); x1 ^= x0; }
#define G_A RND(13) RND(15) RND(26) RND(6)
#define G_B RND(17) RND(29) RND(16) RND(24)
  G_A x0 += k1; x1 += k2 + 1u;
  G_B x0 += k2; x1 += k0 + 2u;
  G_A x0 += k0; x1 += k1 + 3u;
  G_B x0 += k1; x1 += k2 + 4u;
  G_A x0 += k2; x1 += k0 + 5u;
#undef G_A
#undef G_B
#undef RND
  o0 = x0; o1 = x1;
}

// One block per batch row: compute scores, iterative top-32 argmax.
__global__ __launch_bounds__(256) void sample_topk(const float* __restrict__ att,
                                                   float* __restrict__ out_attn,
                                                   int2* __restrict__ ws_yx){
  const int b   = blockIdx.x;
  const int tid = threadIdx.x;
  __shared__ float s[GRID];
  __shared__ float redv[256];
  __shared__ int   redi[256];
  __shared__ float ssum;
  const float* a = att + b * GRID;

  // --- sum(attention row) ---
  float local = 0.f;
  for (int j = tid; j < GRID; j += 256) local += a[j];
  redv[tid] = local; __syncthreads();
  for (int off = 128; off > 0; off >>= 1){
    if (tid < off) redv[tid] += redv[tid+off];
    __syncthreads();
  }
  if (tid == 0) ssum = redv[0];
  __syncthreads();
  const float sum = ssum;

  // --- scores: log(prob + eps) + gumbel ---
  for (int j = tid; j < GRID; j += 256){
    const int e = b * GRID + j;        // flat element in [0, 16384)
    uint32_t o0, o1;
    threefry2x32_k042(0u, (uint32_t)e, o0, o1);   // counter-mode: (hi, lo) = (0, e)
    const uint32_t bits = o0 ^ o1;                // partitionable path XOR-folds
    const float u   = __uint_as_float((bits >> 9) | 0x3F800000u) - 1.0f;  // [0,1)
    const float gum = -logf(-logf(u + EPSF) + EPSF);
    const float prob = a[j] / sum;
    s[j] = logf(prob + EPSF) + gum;
  }
  __syncthreads();

  // --- 32 argmax passes (tie -> lower index, matching lax.top_k) ---
  for (int k = 0; k < NP; ++k){
    float bv = -INFINITY; int bi = GRID;
    for (int j = tid; j < GRID; j += 256){
      const float v = s[j];
      if (v > bv) { bv = v; bi = j; }               // strict > keeps lowest index
    }
    redv[tid] = bv; redi[tid] = bi; __syncthreads();
    for (int off = 128; off > 0; off >>= 1){
      if (tid < off){
        const float ov = redv[tid+off]; const int oi = redi[tid+off];
        if (ov > redv[tid] || (ov == redv[tid] && oi < redi[tid])){
          redv[tid] = ov; redi[tid] = oi;
        }
      }
      __syncthreads();
    }
    if (tid == 0){
      const int idx = redi[0];
      const int row = idx >> 6, col = idx & 63;
      int y0 = row * 32 - 48; y0 = y0 < 0 ? 0 : (y0 > 1920 ? 1920 : y0);
      int x0 = col * 32 - 48; x0 = x0 < 0 ? 0 : (x0 > 1920 ? 1920 : x0);
      ws_yx[b * NP + k]   = make_int2(y0, x0);
      out_attn[b * NP + k] = a[idx] / sum;
      s[idx] = -INFINITY;
    }
    __syncthreads();
  }
}

// One float4 per thread: out[b][n][c][r][0:128] = WSI[b][c][y0+r][x0:x0+128]
__global__ __launch_bounds__(256) void gather_patches(const float* __restrict__ wsi,
                                                      const int2* __restrict__ ws_yx,
                                                      float4* __restrict__ out4){
  const int t    = blockIdx.x * 256 + threadIdx.x;
  const int lane = t & 31;          // which float4 within the 128-float row
  const int row  = t >> 5;          // [0, 4*32*3*128)
  const int r    = row & 127;
  const int tmp  = row >> 7;        // b*96 + n*3 + c
  const int c    = tmp % 3;
  const int bn   = tmp / 3;         // b*32 + n
  const int b    = bn >> 5;
  const int2 yx  = ws_yx[bn];       // (y0, x0); x0 multiple of 16 -> float4 aligned
  const size_t off = ((size_t)((b * 3 + c) * HW + yx.x + r)) * HW + (size_t)yx.y;
  out4[(size_t)row * 32 + lane] =
      *reinterpret_cast<const float4*>(wsi + off + (size_t)lane * 4);
}
} // namespace

extern "C" void kernel_launch(void* const* d_in, const int* in_sizes, int n_in,
                              void* d_out, int out_size, void* d_ws, size_t ws_size,
                              hipStream_t stream) {
  const float* att = (const float*)d_in[2];
  const float* wsi = (const float*)d_in[3];
  float* out       = (float*)d_out;
  float* out_attn  = out + (size_t)B * NP * 3 * PATCH_ * PATCH_;  // 6,291,456
  int2*  ws_yx     = (int2*)d_ws;                                  // 4*32 pairs

  sample_topk<<<B, 256, 0, stream>>>(att, out_attn, ws_yx);

  const int total4 = B * NP * 3 * PATCH_ * PATCH_ / 4;  // 1,572,864 float4s
  gather_patches<<<total4 / 256, 256, 0, stream>>>(wsi, ws_yx, (float4*)out);
}

// Round 3
// 56.675 us; speedup vs baseline: 1.4589x; 1.4589x over previous
//
#include <hip/hip_runtime.h>
#include <stdint.h>
#include <math.h>

// SamplePatches: gumbel top-k sampling (Threefry2x32 counter-mode, key 42) + patch gather.
// Inputs: d_in[0]=x_low (unused), d_in[1]=x_high (unused),
//         d_in[2]=attention [4,64,64] f32, d_in[3]=WSI [4,3,2048,2048] f32.
// Output: patches [4,32,3,128,128] f32 then sampled_attention [4,32] f32, concat flat.
//
// JAX defaults jax_threefry_partitionable=True: bits for element e are
// threefry2x32(key, (hi=0, lo=e)) with the two output words XOR-folded.

namespace {
constexpr int B      = 4;
constexpr int NP     = 32;     // N_PATCHES
constexpr int PATCH_ = 128;
constexpr int GRID   = 4096;   // 64*64 attention cells per batch
constexpr int HW     = 2048;
constexpr int QP     = GRID / 256;   // 16 scores per thread
constexpr float EPSF = 1e-12f;

__device__ inline uint32_t rotl32(uint32_t x, uint32_t r){ return (x<<r)|(x>>(32u-r)); }

// Threefry-2x32 with key (0, 42)  == jax.random.key(42)
__device__ inline void threefry2x32_k042(uint32_t x0, uint32_t x1,
                                         uint32_t& o0, uint32_t& o1){
  const uint32_t k0 = 0u, k1 = 42u;
  const uint32_t k2 = k0 ^ k1 ^ 0x1BD11BDAu;
  x0 += k0; x1 += k1;
#define RND(r) { x0 += x1; x1 = rotl32(x1,(r)); x1 ^= x0; }
#define G_A RND(13) RND(15) RND(26) RND(6)
#define G_B RND(17) RND(29) RND(16) RND(24)
  G_A x0 += k1; x1 += k2 + 1u;
  G_B x0 += k2; x1 += k0 + 2u;
  G_A x0 += k0; x1 += k1 + 3u;
  G_B x0 += k1; x1 += k2 + 4u;
  G_A x0 += k2; x1 += k0 + 5u;
#undef G_A
#undef G_B
#undef RND
  o0 = x0; o1 = x1;
}

// One block per batch row. Scores in registers; per-pass: 6-step wave
// butterfly + 4-entry cross-wave LDS reduce (2 barriers/pass).
__global__ __launch_bounds__(256) void sample_topk(const float* __restrict__ att,
                                                   float* __restrict__ out_attn,
                                                   int2* __restrict__ ws_yx){
  const int b    = blockIdx.x;
  const int tid  = threadIdx.x;
  const int wv   = tid >> 6;        // wave id 0..3
  const int lane = tid & 63;
  __shared__ float redv[4];
  __shared__ int   redi[4];
  __shared__ float ssum;
  const float* a = att + b * GRID;

  // --- sum(attention row): wave butterfly + 4-entry LDS ---
  float local = 0.f;
  #pragma unroll
  for (int q = 0; q < QP; ++q) local += a[q * 256 + tid];
  #pragma unroll
  for (int d = 1; d < 64; d <<= 1) local += __shfl_xor(local, d, 64);
  if (lane == 0) redv[wv] = local;
  __syncthreads();
  if (tid == 0) ssum = redv[0] + redv[1] + redv[2] + redv[3];
  __syncthreads();
  const float sum = ssum;

  // --- scores: log(prob + eps) + gumbel, kept in registers ---
  float sreg[QP];
  #pragma unroll
  for (int q = 0; q < QP; ++q){
    const int j = q * 256 + tid;
    const int e = b * GRID + j;                    // flat element in [0, 16384)
    uint32_t o0, o1;
    threefry2x32_k042(0u, (uint32_t)e, o0, o1);    // counter-mode: (hi, lo) = (0, e)
    const uint32_t bits = o0 ^ o1;                 // partitionable path XOR-folds
    const float u   = __uint_as_float((bits >> 9) | 0x3F800000u) - 1.0f;  // [0,1)
    const float gum = -logf(-logf(u + EPSF) + EPSF);
    sreg[q] = logf(a[j] / sum + EPSF) + gum;
  }

  // thread-local running max (strict > keeps lowest index: j grows with q)
  float lm = -INFINITY; int li = GRID;
  #pragma unroll
  for (int q = 0; q < QP; ++q){
    if (sreg[q] > lm){ lm = sreg[q]; li = q * 256 + tid; }
  }

  // --- 32 argmax passes ---
  for (int k = 0; k < NP; ++k){
    // wave butterfly: (max value, min index on tie)
    float v = lm; int i = li;
    #pragma unroll
    for (int d = 1; d < 64; d <<= 1){
      const float ov = __shfl_xor(v, d, 64);
      const int   oi = __shfl_xor(i, d, 64);
      if (ov > v || (ov == v && oi < i)){ v = ov; i = oi; }
    }
    if (lane == 0){ redv[wv] = v; redi[wv] = i; }
    __syncthreads();
    float bv = redv[0]; int bi = redi[0];
    #pragma unroll
    for (int w = 1; w < 4; ++w){
      const float ov = redv[w]; const int oi = redi[w];
      if (ov > bv || (ov == bv && oi < bi)){ bv = ov; bi = oi; }
    }
    __syncthreads();   // protect redv/redi reuse next pass

    if ((bi & 255) == tid){
      // winner thread: emit, clear, recompute local max (all static indexing)
      if (1){
        const int idx = bi;
        const int row = idx >> 6, col = idx & 63;
        int y0 = row * 32 - 48; y0 = y0 < 0 ? 0 : (y0 > 1920 ? 1920 : y0);
        int x0 = col * 32 - 48; x0 = x0 < 0 ? 0 : (x0 > 1920 ? 1920 : x0);
        ws_yx[b * NP + k]    = make_int2(y0, x0);
        out_attn[b * NP + k] = a[idx] / sum;
      }
      const int qw = bi >> 8;
      #pragma unroll
      for (int q = 0; q < QP; ++q) if (q == qw) sreg[q] = -INFINITY;
      lm = -INFINITY; li = GRID;
      #pragma unroll
      for (int q = 0; q < QP; ++q){
        if (sreg[q] > lm){ lm = sreg[q]; li = q * 256 + tid; }
      }
    }
  }
}

// One float4 per thread: out[b][n][c][r][0:128] = WSI[b][c][y0+r][x0:x0+128]
__global__ __launch_bounds__(256) void gather_patches(const float* __restrict__ wsi,
                                                      const int2* __restrict__ ws_yx,
                                                      float4* __restrict__ out4){
  const int t    = blockIdx.x * 256 + threadIdx.x;
  const int lane = t & 31;          // which float4 within the 128-float row
  const int row  = t >> 5;          // [0, 4*32*3*128)
  const int r    = row & 127;
  const int tmp  = row >> 7;        // b*96 + n*3 + c
  const int c    = tmp % 3;
  const int bn   = tmp / 3;         // b*32 + n
  const int b    = bn >> 5;
  const int2 yx  = ws_yx[bn];       // (y0, x0); x0 multiple of 16 -> float4 aligned
  const size_t off = ((size_t)((b * 3 + c) * HW + yx.x + r)) * HW + (size_t)yx.y;
  out4[(size_t)row * 32 + lane] =
      *reinterpret_cast<const float4*>(wsi + off + (size_t)lane * 4);
}
} // namespace

extern "C" void kernel_launch(void* const* d_in, const int* in_sizes, int n_in,
                              void* d_out, int out_size, void* d_ws, size_t ws_size,
                              hipStream_t stream) {
  const float* att = (const float*)d_in[2];
  const float* wsi = (const float*)d_in[3];
  float* out       = (float*)d_out;
  float* out_attn  = out + (size_t)B * NP * 3 * PATCH_ * PATCH_;  // 6,291,456
  int2*  ws_yx     = (int2*)d_ws;                                  // 4*32 pairs

  sample_topk<<<B, 256, 0, stream>>>(att, out_attn, ws_yx);

  const int total4 = B * NP * 3 * PATCH_ * PATCH_ / 4;  // 1,572,864 float4s
  gather_patches<<<total4 / 256, 256, 0, stream>>>(wsi, ws_yx, (float4*)out);
}

// Round 4
// 44.723 us; speedup vs baseline: 1.8488x; 1.2672x over previous
//
#include <hip/hip_runtime.h>
#include <stdint.h>
#include <math.h>

// SamplePatches: gumbel top-k sampling (Threefry2x32 counter-mode, key 42) + patch gather.
// Inputs: d_in[0]=x_low (unused), d_in[1]=x_high (unused),
//         d_in[2]=attention [4,64,64] f32, d_in[3]=WSI [4,3,2048,2048] f32.
// Output: patches [4,32,3,128,128] f32 then sampled_attention [4,32] f32, concat flat.
//
// JAX defaults jax_threefry_partitionable=True: bits for element e are
// threefry2x32(key, (hi=0, lo=e)) with the two output words XOR-folded.

namespace {
constexpr int B      = 4;
constexpr int NP     = 32;     // N_PATCHES
constexpr int PATCH_ = 128;
constexpr int GRID   = 4096;   // 64*64 attention cells per batch
constexpr int HW     = 2048;
constexpr int QP     = GRID / 256;   // 16 scores per thread
constexpr float EPSF = 1e-12f;

__device__ inline uint32_t rotl32(uint32_t x, uint32_t r){ return (x<<r)|(x>>(32u-r)); }

// Threefry-2x32 with key (0, 42)  == jax.random.key(42)
__device__ inline void threefry2x32_k042(uint32_t x0, uint32_t x1,
                                         uint32_t& o0, uint32_t& o1){
  const uint32_t k0 = 0u, k1 = 42u;
  const uint32_t k2 = k0 ^ k1 ^ 0x1BD11BDAu;
  x0 += k0; x1 += k1;
#define RND(r) { x0 += x1; x1 = rotl32(x1,(r)); x1 ^= x0; }
#define G_A RND(13) RND(15) RND(26) RND(6)
#define G_B RND(17) RND(29) RND(16) RND(24)
  G_A x0 += k1; x1 += k2 + 1u;
  G_B x0 += k2; x1 += k0 + 2u;
  G_A x0 += k0; x1 += k1 + 3u;
  G_B x0 += k1; x1 += k2 + 4u;
  G_A x0 += k2; x1 += k0 + 5u;
#undef G_A
#undef G_B
#undef RND
  o0 = x0; o1 = x1;
}

// Monotone packing: key = mono(float) || (4095 - j). max key == (max val, min idx).
__device__ inline unsigned long long pack_key(float v, int j){
  const uint32_t bits = __float_as_uint(v);
  const uint32_t m = (bits & 0x80000000u) ? ~bits : (bits | 0x80000000u);
  return ((unsigned long long)m << 32) | (uint32_t)(GRID - 1 - j);
}

// One block per batch row. Scores in registers; per pass: 6-step u64 butterfly
// + parity-buffered 4-entry cross-wave LDS reduce (ONE barrier, NO global ops).
__global__ __launch_bounds__(256) void sample_topk(const float* __restrict__ att,
                                                   float* __restrict__ out_attn,
                                                   int2* __restrict__ ws_yx){
  const int b    = blockIdx.x;
  const int tid  = threadIdx.x;
  const int wv   = tid >> 6;        // wave id 0..3
  const int lane = tid & 63;
  __shared__ unsigned long long kred[2][4];
  __shared__ float redv[4];
  __shared__ float ssum;
  __shared__ int   residx[NP];
  __shared__ float resatt[NP];
  const float* a = att + b * GRID;

  // --- load attention row into registers (only global reads in this kernel) ---
  float areg[QP];
  #pragma unroll
  for (int q = 0; q < QP; ++q) areg[q] = a[q * 256 + tid];

  // --- sum(attention row): wave butterfly + 4-entry LDS ---
  float local = 0.f;
  #pragma unroll
  for (int q = 0; q < QP; ++q) local += areg[q];
  #pragma unroll
  for (int d = 1; d < 64; d <<= 1) local += __shfl_xor(local, d, 64);
  if (lane == 0) redv[wv] = local;
  __syncthreads();
  if (tid == 0) ssum = redv[0] + redv[1] + redv[2] + redv[3];
  __syncthreads();
  const float sum = ssum;

  // --- scores: log(prob + eps) + gumbel, all in registers ---
  float sreg[QP], preg[QP];
  #pragma unroll
  for (int q = 0; q < QP; ++q){
    const int j = q * 256 + tid;
    const int e = b * GRID + j;                    // flat element in [0, 16384)
    uint32_t o0, o1;
    threefry2x32_k042(0u, (uint32_t)e, o0, o1);    // counter-mode: (hi, lo) = (0, e)
    const uint32_t bits = o0 ^ o1;                 // partitionable path XOR-folds
    const float u   = __uint_as_float((bits >> 9) | 0x3F800000u) - 1.0f;  // [0,1)
    const float gum = -logf(-logf(u + EPSF) + EPSF);
    const float prob = areg[q] / sum;
    preg[q] = prob;
    sreg[q] = logf(prob + EPSF) + gum;
  }

  // thread-local running max as packed key
  unsigned long long lk = 0ull;
  #pragma unroll
  for (int q = 0; q < QP; ++q){
    const unsigned long long key = pack_key(sreg[q], q * 256 + tid);
    if (key > lk) lk = key;
  }

  // --- 32 argmax passes, one barrier each, no global memory ops ---
  for (int k = 0; k < NP; ++k){
    unsigned long long v = lk;
    #pragma unroll
    for (int d = 1; d < 64; d <<= 1){
      const unsigned long long o = __shfl_xor(v, d, 64);
      if (o > v) v = o;
    }
    if (lane == 0) kred[k & 1][wv] = v;
    __syncthreads();
    unsigned long long bk = kred[k & 1][0];
    #pragma unroll
    for (int w = 1; w < 4; ++w){
      const unsigned long long o = kred[k & 1][w];
      if (o > bk) bk = o;
    }
    const int bj = GRID - 1 - (int)(uint32_t)(bk & 0xFFFFFFFFull);

    if ((bj & 255) == tid){
      // winner thread: record to LDS, clear, recompute local max (static indexing)
      residx[k] = bj;
      const int qw = bj >> 8;
      float pa = 0.f;
      #pragma unroll
      for (int q = 0; q < QP; ++q){
        if (q == qw){ pa = preg[q]; sreg[q] = -INFINITY; }
      }
      resatt[k] = pa;
      lk = 0ull;
      #pragma unroll
      for (int q = 0; q < QP; ++q){
        const unsigned long long key = pack_key(sreg[q], q * 256 + tid);
        if (key > lk) lk = key;
      }
    }
    // parity buffering on kred makes a trailing barrier unnecessary:
    // pass k+2's write to kred[k&1] is already separated from pass k's
    // reads by the pass-k+1 barrier.
  }
  __syncthreads();

  // --- final output phase: the only global writes ---
  if (tid < NP){
    const int idx = residx[tid];
    const int row = idx >> 6, col = idx & 63;
    int y0 = row * 32 - 48; y0 = y0 < 0 ? 0 : (y0 > 1920 ? 1920 : y0);
    int x0 = col * 32 - 48; x0 = x0 < 0 ? 0 : (x0 > 1920 ? 1920 : x0);
    ws_yx[b * NP + tid]    = make_int2(y0, x0);
    out_attn[b * NP + tid] = resatt[tid];
  }
}

// One float4 per thread: out[b][n][c][r][0:128] = WSI[b][c][y0+r][x0:x0+128]
__global__ __launch_bounds__(256) void gather_patches(const float* __restrict__ wsi,
                                                      const int2* __restrict__ ws_yx,
                                                      float4* __restrict__ out4){
  const int t    = blockIdx.x * 256 + threadIdx.x;
  const int lane = t & 31;          // which float4 within the 128-float row
  const int row  = t >> 5;          // [0, 4*32*3*128)
  const int r    = row & 127;
  const int tmp  = row >> 7;        // b*96 + n*3 + c
  const int c    = tmp % 3;
  const int bn   = tmp / 3;         // b*32 + n
  const int b    = bn >> 5;
  const int2 yx  = ws_yx[bn];       // (y0, x0); x0 multiple of 16 -> float4 aligned
  const size_t off = ((size_t)((b * 3 + c) * HW + yx.x + r)) * HW + (size_t)yx.y;
  out4[(size_t)row * 32 + lane] =
      *reinterpret_cast<const float4*>(wsi + off + (size_t)lane * 4);
}
} // namespace

extern "C" void kernel_launch(void* const* d_in, const int* in_sizes, int n_in,
                              void* d_out, int out_size, void* d_ws, size_t ws_size,
                              hipStream_t stream) {
  const float* att = (const float*)d_in[2];
  const float* wsi = (const float*)d_in[3];
  float* out       = (float*)d_out;
  float* out_attn  = out + (size_t)B * NP * 3 * PATCH_ * PATCH_;  // 6,291,456
  int2*  ws_yx     = (int2*)d_ws;                                  // 4*32 pairs

  sample_topk<<<B, 256, 0, stream>>>(att, out_attn, ws_yx);

  const int total4 = B * NP * 3 * PATCH_ * PATCH_ / 4;  // 1,572,864 float4s
  gather_patches<<<total4 / 256, 256, 0, stream>>>(wsi, ws_yx, (float4*)out);
}

// Round 5
// 42.608 us; speedup vs baseline: 1.9406x; 1.0496x over previous
//
#include <hip/hip_runtime.h>
#include <stdint.h>
#include <math.h>

// SamplePatches: gumbel top-k sampling (Threefry2x32 counter-mode, key 42) + patch gather.
// Inputs: d_in[0]=x_low (unused), d_in[1]=x_high (unused),
//         d_in[2]=attention [4,64,64] f32, d_in[3]=WSI [4,3,2048,2048] f32.
// Output: patches [4,32,3,128,128] f32 then sampled_attention [4,32] f32, concat flat.
//
// JAX defaults jax_threefry_partitionable=True: bits for element e are
// threefry2x32(key, (hi=0, lo=e)) with the two output words XOR-folded.
//
// Selection: per-wave top-32 via DPP f32 max-reduce (no barriers in pass loop),
// then a rank-merge of the 4x32 candidates. Total order = (value desc, j asc),
// identical to lax.top_k.

namespace {
constexpr int B      = 4;
constexpr int NP     = 32;     // N_PATCHES
constexpr int PATCH_ = 128;
constexpr int GRID   = 4096;   // 64*64 attention cells per batch
constexpr int HW     = 2048;
constexpr int QP     = 16;     // scores per thread: 4 waves x 64 lanes x 16
constexpr float EPSF = 1e-12f;

__device__ inline uint32_t rotl32(uint32_t x, uint32_t r){ return (x<<r)|(x>>(32u-r)); }

// Threefry-2x32 with key (0, 42)  == jax.random.key(42)
__device__ inline void threefry2x32_k042(uint32_t x0, uint32_t x1,
                                         uint32_t& o0, uint32_t& o1){
  const uint32_t k0 = 0u, k1 = 42u;
  const uint32_t k2 = k0 ^ k1 ^ 0x1BD11BDAu;
  x0 += k0; x1 += k1;
#define RND(r) { x0 += x1; x1 = rotl32(x1,(r)); x1 ^= x0; }
#define G_A RND(13) RND(15) RND(26) RND(6)
#define G_B RND(17) RND(29) RND(16) RND(24)
  G_A x0 += k1; x1 += k2 + 1u;
  G_B x0 += k2; x1 += k0 + 2u;
  G_A x0 += k0; x1 += k1 + 3u;
  G_B x0 += k1; x1 += k2 + 4u;
  G_A x0 += k2; x1 += k0 + 5u;
#undef G_A
#undef G_B
#undef RND
  o0 = x0; o1 = x1;
}

// Monotone map: u32 compare order == f32 value order.
__device__ inline uint32_t mono_f32(float v){
  const uint32_t bits = __float_as_uint(v);
  return (bits & 0x80000000u) ? ~bits : (bits | 0x80000000u);
}

// One DPP max step: combine with a lane-shifted copy. Lanes with an invalid
// source keep old==own value (bound_ctrl=false), a no-op for max.
template<int CTRL>
__device__ __forceinline__ float dpp_max_step(float v){
  const int vi = __float_as_int(v);
  const int oi = __builtin_amdgcn_update_dpp(vi, vi, CTRL, 0xF, 0xF, false);
  return fmaxf(v, __int_as_float(oi));
}

// Full wave64 max, broadcast to all lanes via readlane(63).
__device__ __forceinline__ float wave_max_bcast(float v){
  v = dpp_max_step<0x111>(v);   // row_shr:1
  v = dpp_max_step<0x112>(v);   // row_shr:2
  v = dpp_max_step<0x114>(v);   // row_shr:4
  v = dpp_max_step<0x118>(v);   // row_shr:8  -> lane15 of each row = row max
  v = dpp_max_step<0x142>(v);   // row_bcast:15
  v = dpp_max_step<0x143>(v);   // row_bcast:31 -> lane63 = wave max
  return __int_as_float(__builtin_amdgcn_readlane(__float_as_int(v), 63));
}

// One block per batch row.
__global__ __launch_bounds__(256) void sample_topk(const float* __restrict__ att,
                                                   float* __restrict__ out_attn,
                                                   int2* __restrict__ ws_yx){
  const int b    = blockIdx.x;
  const int tid  = threadIdx.x;
  const int wv   = tid >> 6;        // wave id 0..3
  const int lane = tid & 63;
  __shared__ unsigned long long ckey[4 * NP];  // per-wave sorted candidates
  __shared__ float             cprob[4 * NP];
  __shared__ float redv[4];
  __shared__ float ssum;
  const float* a = att + b * GRID;

  // --- load 16 contiguous floats per thread (4x float4): j = wv*1024 + lane*16 + q ---
  const float4* a4 = reinterpret_cast<const float4*>(a + (wv << 10) + (lane << 4));
  const float4 v0 = a4[0], v1 = a4[1], v2 = a4[2], v3 = a4[3];
  float areg[QP] = {v0.x,v0.y,v0.z,v0.w, v1.x,v1.y,v1.z,v1.w,
                    v2.x,v2.y,v2.z,v2.w, v3.x,v3.y,v3.z,v3.w};

  // --- sum(attention row) ---
  float local = 0.f;
  #pragma unroll
  for (int q = 0; q < QP; ++q) local += areg[q];
  #pragma unroll
  for (int d = 1; d < 64; d <<= 1) local += __shfl_xor(local, d, 64);
  if (lane == 0) redv[wv] = local;
  __syncthreads();
  if (tid == 0) ssum = redv[0] + redv[1] + redv[2] + redv[3];
  __syncthreads();
  const float sum = ssum;

  // --- scores: log(prob + eps) + gumbel, all in registers ---
  float sreg[QP], preg[QP];
  #pragma unroll
  for (int q = 0; q < QP; ++q){
    const int j = (wv << 10) + (lane << 4) + q;
    const int e = b * GRID + j;                    // flat element in [0, 16384)
    uint32_t o0, o1;
    threefry2x32_k042(0u, (uint32_t)e, o0, o1);    // counter-mode: (hi, lo) = (0, e)
    const uint32_t bits = o0 ^ o1;                 // partitionable path XOR-folds
    const float u   = __uint_as_float((bits >> 9) | 0x3F800000u) - 1.0f;  // [0,1)
    const float gum = -logf(-logf(u + EPSF) + EPSF);
    const float prob = areg[q] / sum;
    preg[q] = prob;
    sreg[q] = logf(prob + EPSF) + gum;
  }

  float lm = -INFINITY;
  #pragma unroll
  for (int q = 0; q < QP; ++q) lm = fmaxf(lm, sreg[q]);

  // --- phase 1: per-wave top-32, no barriers, DPP reduce per pass ---
  for (int k = 0; k < NP; ++k){
    const float bv = wave_max_bcast(lm);
    const unsigned long long mask = __ballot(lm == bv);
    const int wl = (int)(__ffsll(mask) - 1);       // lowest lane -> lowest j
    if (lane == wl){
      int qs = -1; float pa = 0.f;
      #pragma unroll
      for (int q = 0; q < QP; ++q){
        if (qs < 0 && sreg[q] == bv){ qs = q; pa = preg[q]; sreg[q] = -INFINITY; }
      }
      const int j = (wv << 10) + (lane << 4) + qs;
      ckey[wv * NP + k]  = ((unsigned long long)mono_f32(bv) << 32)
                         | (uint32_t)(GRID - 1 - j);
      cprob[wv * NP + k] = pa;
      lm = -INFINITY;
      #pragma unroll
      for (int q = 0; q < QP; ++q) lm = fmaxf(lm, sreg[q]);
    }
  }
  __syncthreads();

  // --- phase 2: rank-merge 128 candidates; rank < 32 -> emit at that rank ---
  if (tid < 4 * NP){
    const unsigned long long mykey = ckey[tid];
    int rank = 0;
    for (int c = 0; c < 4 * NP; ++c) rank += (ckey[c] > mykey) ? 1 : 0;
    if (rank < NP){
      const int j   = GRID - 1 - (int)(uint32_t)(mykey & 0xFFFFFFFFull);
      const int row = j >> 6, col = j & 63;
      int y0 = row * 32 - 48; y0 = y0 < 0 ? 0 : (y0 > 1920 ? 1920 : y0);
      int x0 = col * 32 - 48; x0 = x0 < 0 ? 0 : (x0 > 1920 ? 1920 : x0);
      ws_yx[b * NP + rank]    = make_int2(y0, x0);
      out_attn[b * NP + rank] = cprob[tid];
    }
  }
}

// One float4 per thread: out[b][n][c][r][0:128] = WSI[b][c][y0+r][x0:x0+128]
__global__ __launch_bounds__(256) void gather_patches(const float* __restrict__ wsi,
                                                      const int2* __restrict__ ws_yx,
                                                      float4* __restrict__ out4){
  const int t    = blockIdx.x * 256 + threadIdx.x;
  const int lane = t & 31;          // which float4 within the 128-float row
  const int row  = t >> 5;          // [0, 4*32*3*128)
  const int r    = row & 127;
  const int tmp  = row >> 7;        // b*96 + n*3 + c
  const int c    = tmp % 3;
  const int bn   = tmp / 3;         // b*32 + n
  const int b    = bn >> 5;
  const int2 yx  = ws_yx[bn];       // (y0, x0); x0 multiple of 16 -> float4 aligned
  const size_t off = ((size_t)((b * 3 + c) * HW + yx.x + r)) * HW + (size_t)yx.y;
  out4[(size_t)row * 32 + lane] =
      *reinterpret_cast<const float4*>(wsi + off + (size_t)lane * 4);
}
} // namespace

extern "C" void kernel_launch(void* const* d_in, const int* in_sizes, int n_in,
                              void* d_out, int out_size, void* d_ws, size_t ws_size,
                              hipStream_t stream) {
  const float* att = (const float*)d_in[2];
  const float* wsi = (const float*)d_in[3];
  float* out       = (float*)d_out;
  float* out_attn  = out + (size_t)B * NP * 3 * PATCH_ * PATCH_;  // 6,291,456
  int2*  ws_yx     = (int2*)d_ws;                                  // 4*32 pairs

  sample_topk<<<B, 256, 0, stream>>>(att, out_attn, ws_yx);

  const int total4 = B * NP * 3 * PATCH_ * PATCH_ / 4;  // 1,572,864 float4s
  gather_patches<<<total4 / 256, 256, 0, stream>>>(wsi, ws_yx, (float4*)out);
}

// Round 6
// 39.735 us; speedup vs baseline: 2.0809x; 1.0723x over previous
//
#include <hip/hip_runtime.h>
#include <stdint.h>
#include <math.h>

// SamplePatches: gumbel top-k sampling (Threefry2x32 counter-mode, key 42) + patch gather.
// Inputs: d_in[0]=x_low (unused), d_in[1]=x_high (unused),
//         d_in[2]=attention [4,64,64] f32, d_in[3]=WSI [4,3,2048,2048] f32.
// Output: patches [4,32,3,128,128] f32 then sampled_attention [4,32] f32, concat flat.
//
// JAX defaults jax_threefry_partitionable=True: bits for element e are
// threefry2x32(key, (hi=0, lo=e)) with the two output words XOR-folded.
//
// Selection: 16 waves/block, per-wave top-32 via DPP f32 max-reduce (no barriers
// in pass loop), then rank-merge of 16x32 candidates. Total order =
// (value desc, j asc), identical to lax.top_k.

namespace {
constexpr int B      = 4;
constexpr int NP     = 32;     // N_PATCHES
constexpr int PATCH_ = 128;
constexpr int GRID   = 4096;   // 64*64 attention cells per batch
constexpr int HW     = 2048;
constexpr int NT     = 1024;   // threads per sampling block
constexpr int NW     = NT / 64;          // 16 waves
constexpr int QP     = GRID / NT;        // 4 scores per thread
constexpr int NCAND  = NW * NP;          // 512 merge candidates
constexpr float EPSF = 1e-12f;

__device__ inline uint32_t rotl32(uint32_t x, uint32_t r){ return (x<<r)|(x>>(32u-r)); }

// Threefry-2x32 with key (0, 42)  == jax.random.key(42)
__device__ inline void threefry2x32_k042(uint32_t x0, uint32_t x1,
                                         uint32_t& o0, uint32_t& o1){
  const uint32_t k0 = 0u, k1 = 42u;
  const uint32_t k2 = k0 ^ k1 ^ 0x1BD11BDAu;
  x0 += k0; x1 += k1;
#define RND(r) { x0 += x1; x1 = rotl32(x1,(r)); x1 ^= x0; }
#define G_A RND(13) RND(15) RND(26) RND(6)
#define G_B RND(17) RND(29) RND(16) RND(24)
  G_A x0 += k1; x1 += k2 + 1u;
  G_B x0 += k2; x1 += k0 + 2u;
  G_A x0 += k0; x1 += k1 + 3u;
  G_B x0 += k1; x1 += k2 + 4u;
  G_A x0 += k2; x1 += k0 + 5u;
#undef G_A
#undef G_B
#undef RND
  o0 = x0; o1 = x1;
}

// Monotone map: u32 compare order == f32 value order.
__device__ inline uint32_t mono_f32(float v){
  const uint32_t bits = __float_as_uint(v);
  return (bits & 0x80000000u) ? ~bits : (bits | 0x80000000u);
}

// One DPP max step: combine with a lane-shifted copy (invalid srcs keep own value).
template<int CTRL>
__device__ __forceinline__ float dpp_max_step(float v){
  const int vi = __float_as_int(v);
  const int oi = __builtin_amdgcn_update_dpp(vi, vi, CTRL, 0xF, 0xF, false);
  return fmaxf(v, __int_as_float(oi));
}

// Full wave64 max, broadcast to all lanes via readlane(63).
__device__ __forceinline__ float wave_max_bcast(float v){
  v = dpp_max_step<0x111>(v);   // row_shr:1
  v = dpp_max_step<0x112>(v);   // row_shr:2
  v = dpp_max_step<0x114>(v);   // row_shr:4
  v = dpp_max_step<0x118>(v);   // row_shr:8  -> lane15 of each row = row max
  v = dpp_max_step<0x142>(v);   // row_bcast:15
  v = dpp_max_step<0x143>(v);   // row_bcast:31 -> lane63 = wave max
  return __int_as_float(__builtin_amdgcn_readlane(__float_as_int(v), 63));
}

// One block (1024 threads, 16 waves) per batch row.
__global__ __launch_bounds__(NT) void sample_topk(const float* __restrict__ att,
                                                  float* __restrict__ out_attn,
                                                  int2* __restrict__ ws_yx){
  const int b    = blockIdx.x;
  const int tid  = threadIdx.x;
  const int wv   = tid >> 6;        // wave id 0..15
  const int lane = tid & 63;
  __shared__ unsigned long long ckey[NCAND];   // per-wave sorted candidates
  __shared__ float             cprob[NCAND];
  __shared__ float redv[NW];
  __shared__ float ssum;
  const float* a = att + b * GRID;

  // --- one float4 per thread: j = tid*4 + q (contiguous) ---
  const float4 va = reinterpret_cast<const float4*>(a)[tid];
  float areg[QP] = {va.x, va.y, va.z, va.w};

  // --- sum(attention row) ---
  float local = areg[0] + areg[1] + areg[2] + areg[3];
  #pragma unroll
  for (int d = 1; d < 64; d <<= 1) local += __shfl_xor(local, d, 64);
  if (lane == 0) redv[wv] = local;
  __syncthreads();
  if (tid == 0){
    float s = 0.f;
    #pragma unroll
    for (int w = 0; w < NW; ++w) s += redv[w];
    ssum = s;
  }
  __syncthreads();
  const float sum = ssum;

  // --- scores: log(prob + eps) + gumbel, all in registers ---
  float sreg[QP], preg[QP];
  #pragma unroll
  for (int q = 0; q < QP; ++q){
    const int j = (tid << 2) + q;
    const int e = b * GRID + j;                    // flat element in [0, 16384)
    uint32_t o0, o1;
    threefry2x32_k042(0u, (uint32_t)e, o0, o1);    // counter-mode: (hi, lo) = (0, e)
    const uint32_t bits = o0 ^ o1;                 // partitionable path XOR-folds
    const float u   = __uint_as_float((bits >> 9) | 0x3F800000u) - 1.0f;  // [0,1)
    const float gum = -logf(-logf(u + EPSF) + EPSF);
    const float prob = areg[q] / sum;
    preg[q] = prob;
    sreg[q] = logf(prob + EPSF) + gum;
  }

  float lm = fmaxf(fmaxf(sreg[0], sreg[1]), fmaxf(sreg[2], sreg[3]));

  // --- phase 1: per-wave top-32 over its 256 elements, no barriers ---
  for (int k = 0; k < NP; ++k){
    const float bv = wave_max_bcast(lm);
    const unsigned long long mask = __ballot(lm == bv);
    const int wl = (int)(__ffsll(mask) - 1);       // lowest lane -> lowest j
    if (lane == wl){
      int qs = -1; float pa = 0.f;
      #pragma unroll
      for (int q = 0; q < QP; ++q){
        if (qs < 0 && sreg[q] == bv){ qs = q; pa = preg[q]; sreg[q] = -INFINITY; }
      }
      const int j = (tid << 2) + qs;
      ckey[wv * NP + k]  = ((unsigned long long)mono_f32(bv) << 32)
                         | (uint32_t)(GRID - 1 - j);
      cprob[wv * NP + k] = pa;
      lm = fmaxf(fmaxf(sreg[0], sreg[1]), fmaxf(sreg[2], sreg[3]));
    }
  }
  __syncthreads();

  // --- phase 2: rank-merge candidates; rank < 32 -> emit at that rank ---
  if (tid < NCAND){
    const unsigned long long mykey = ckey[tid];
    int rank = 0;
    #pragma unroll 4
    for (int c = 0; c < NCAND; ++c) rank += (ckey[c] > mykey) ? 1 : 0;
    if (rank < NP){
      const int j   = GRID - 1 - (int)(uint32_t)(mykey & 0xFFFFFFFFull);
      const int row = j >> 6, col = j & 63;
      int y0 = row * 32 - 48; y0 = y0 < 0 ? 0 : (y0 > 1920 ? 1920 : y0);
      int x0 = col * 32 - 48; x0 = x0 < 0 ? 0 : (x0 > 1920 ? 1920 : x0);
      ws_yx[b * NP + rank]    = make_int2(y0, x0);
      out_attn[b * NP + rank] = cprob[tid];
    }
  }
}

// Two float4s per thread: out[b][n][c][r][:] = WSI[b][c][y0+r][x0:x0+128]
__global__ __launch_bounds__(256) void gather_patches(const float* __restrict__ wsi,
                                                      const int2* __restrict__ ws_yx,
                                                      float4* __restrict__ out4){
  const int t    = blockIdx.x * 256 + threadIdx.x;
  const int h    = t & 15;          // float4 pair index within the 128-float row
  const int row  = t >> 4;          // [0, 4*32*3*128)
  const int r    = row & 127;
  const int tmp  = row >> 7;        // b*96 + n*3 + c
  const int c    = tmp % 3;
  const int bn   = tmp / 3;         // b*32 + n
  const int b    = bn >> 5;
  const int2 yx  = ws_yx[bn];       // (y0, x0); x0 multiple of 16 -> float4 aligned
  const float4* src = reinterpret_cast<const float4*>(
      wsi + ((size_t)((b * 3 + c) * HW + yx.x + r)) * HW + (size_t)yx.y);
  float4* dst = out4 + (size_t)row * 32;
  dst[h]      = src[h];
  dst[h + 16] = src[h + 16];
}
} // namespace

extern "C" void kernel_launch(void* const* d_in, const int* in_sizes, int n_in,
                              void* d_out, int out_size, void* d_ws, size_t ws_size,
                              hipStream_t stream) {
  const float* att = (const float*)d_in[2];
  const float* wsi = (const float*)d_in[3];
  float* out       = (float*)d_out;
  float* out_attn  = out + (size_t)B * NP * 3 * PATCH_ * PATCH_;  // 6,291,456
  int2*  ws_yx     = (int2*)d_ws;                                  // 4*32 pairs

  sample_topk<<<B, NT, 0, stream>>>(att, out_attn, ws_yx);

  const int total_t = B * NP * 3 * PATCH_ * PATCH_ / 8;  // 786,432 threads
  gather_patches<<<total_t / 256, 256, 0, stream>>>(wsi, ws_yx, (float4*)out);
}

// Round 7
// 32.716 us; speedup vs baseline: 2.5273x; 1.2145x over previous
//
#include <hip/hip_runtime.h>
#include <stdint.h>
#include <math.h>

// SamplePatches: gumbel top-k sampling (Threefry2x32 counter-mode, key 42) + patch gather.
// Inputs: d_in[0]=x_low (unused), d_in[1]=x_high (unused),
//         d_in[2]=attention [4,64,64] f32, d_in[3]=WSI [4,3,2048,2048] f32.
// Output: patches [4,32,3,128,128] f32 then sampled_attention [4,32] f32, concat flat.
//
// JAX defaults jax_threefry_partitionable=True: bits for element e are
// threefry2x32(key, (hi=0, lo=e)) with the two output words XOR-folded.
//
// Selection: 16 waves/block, per-wave top-32 via DPP f32 max-reduce (no barriers
// in pass loop; each wave's list is emitted in strictly descending key order),
// then rank-merge via per-list binary search. Total order = (value desc, j asc),
// identical to lax.top_k.

namespace {
constexpr int B      = 4;
constexpr int NP     = 32;     // N_PATCHES
constexpr int PATCH_ = 128;
constexpr int GRID   = 4096;   // 64*64 attention cells per batch
constexpr int HW     = 2048;
constexpr int NT     = 1024;   // threads per sampling block
constexpr int NW     = NT / 64;          // 16 waves
constexpr int QP     = GRID / NT;        // 4 scores per thread
constexpr int NCAND  = NW * NP;          // 512 merge candidates
constexpr int GB     = 2048;   // gather blocks (grid-stride)
constexpr float EPSF = 1e-12f;

typedef float f32x4 __attribute__((ext_vector_type(4)));

__device__ inline uint32_t rotl32(uint32_t x, uint32_t r){ return (x<<r)|(x>>(32u-r)); }

// Threefry-2x32 with key (0, 42)  == jax.random.key(42)
__device__ inline void threefry2x32_k042(uint32_t x0, uint32_t x1,
                                         uint32_t& o0, uint32_t& o1){
  const uint32_t k0 = 0u, k1 = 42u;
  const uint32_t k2 = k0 ^ k1 ^ 0x1BD11BDAu;
  x0 += k0; x1 += k1;
#define RND(r) { x0 += x1; x1 = rotl32(x1,(r)); x1 ^= x0; }
#define G_A RND(13) RND(15) RND(26) RND(6)
#define G_B RND(17) RND(29) RND(16) RND(24)
  G_A x0 += k1; x1 += k2 + 1u;
  G_B x0 += k2; x1 += k0 + 2u;
  G_A x0 += k0; x1 += k1 + 3u;
  G_B x0 += k1; x1 += k2 + 4u;
  G_A x0 += k2; x1 += k0 + 5u;
#undef G_A
#undef G_B
#undef RND
  o0 = x0; o1 = x1;
}

// Monotone map: u32 compare order == f32 value order.
__device__ inline uint32_t mono_f32(float v){
  const uint32_t bits = __float_as_uint(v);
  return (bits & 0x80000000u) ? ~bits : (bits | 0x80000000u);
}

// One DPP max step: combine with a lane-shifted copy (invalid srcs keep own value).
template<int CTRL>
__device__ __forceinline__ float dpp_max_step(float v){
  const int vi = __float_as_int(v);
  const int oi = __builtin_amdgcn_update_dpp(vi, vi, CTRL, 0xF, 0xF, false);
  return fmaxf(v, __int_as_float(oi));
}

// Full wave64 max, broadcast to all lanes via readlane(63).
__device__ __forceinline__ float wave_max_bcast(float v){
  v = dpp_max_step<0x111>(v);   // row_shr:1
  v = dpp_max_step<0x112>(v);   // row_shr:2
  v = dpp_max_step<0x114>(v);   // row_shr:4
  v = dpp_max_step<0x118>(v);   // row_shr:8  -> lane15 of each row = row max
  v = dpp_max_step<0x142>(v);   // row_bcast:15
  v = dpp_max_step<0x143>(v);   // row_bcast:31 -> lane63 = wave max
  return __int_as_float(__builtin_amdgcn_readlane(__float_as_int(v), 63));
}

// One block (1024 threads, 16 waves) per batch row.
__global__ __launch_bounds__(NT) void sample_topk(const float* __restrict__ att,
                                                  float* __restrict__ out_attn,
                                                  int2* __restrict__ ws_yx){
  const int b    = blockIdx.x;
  const int tid  = threadIdx.x;
  const int wv   = tid >> 6;        // wave id 0..15
  const int lane = tid & 63;
  __shared__ unsigned long long ckey[NCAND];   // per-wave DESCENDING candidate lists
  __shared__ float             cprob[NCAND];
  __shared__ float redv[NW];
  __shared__ float ssum;
  const float* a = att + b * GRID;

  // --- one float4 per thread: j = tid*4 + q (contiguous) ---
  const float4 va = reinterpret_cast<const float4*>(a)[tid];
  float areg[QP] = {va.x, va.y, va.z, va.w};

  // --- sum(attention row) ---
  float local = areg[0] + areg[1] + areg[2] + areg[3];
  #pragma unroll
  for (int d = 1; d < 64; d <<= 1) local += __shfl_xor(local, d, 64);
  if (lane == 0) redv[wv] = local;
  __syncthreads();
  if (tid == 0){
    float s = 0.f;
    #pragma unroll
    for (int w = 0; w < NW; ++w) s += redv[w];
    ssum = s;
  }
  __syncthreads();
  const float sum = ssum;

  // --- scores: log(prob + eps) + gumbel, all in registers ---
  float sreg[QP], preg[QP];
  #pragma unroll
  for (int q = 0; q < QP; ++q){
    const int j = (tid << 2) + q;
    const int e = b * GRID + j;                    // flat element in [0, 16384)
    uint32_t o0, o1;
    threefry2x32_k042(0u, (uint32_t)e, o0, o1);    // counter-mode: (hi, lo) = (0, e)
    const uint32_t bits = o0 ^ o1;                 // partitionable path XOR-folds
    const float u   = __uint_as_float((bits >> 9) | 0x3F800000u) - 1.0f;  // [0,1)
    const float gum = -logf(-logf(u + EPSF) + EPSF);
    const float prob = areg[q] / sum;
    preg[q] = prob;
    sreg[q] = logf(prob + EPSF) + gum;
  }

  float lm = fmaxf(fmaxf(sreg[0], sreg[1]), fmaxf(sreg[2], sreg[3]));

  // --- phase 1: per-wave top-32 over its 256 elements, no barriers ---
  for (int k = 0; k < NP; ++k){
    const float bv = wave_max_bcast(lm);
    const unsigned long long mask = __ballot(lm == bv);
    const int wl = (int)(__ffsll(mask) - 1);       // lowest lane -> lowest j
    if (lane == wl){
      int qs = -1; float pa = 0.f;
      #pragma unroll
      for (int q = 0; q < QP; ++q){
        if (qs < 0 && sreg[q] == bv){ qs = q; pa = preg[q]; sreg[q] = -INFINITY; }
      }
      const int j = (tid << 2) + qs;
      ckey[wv * NP + k]  = ((unsigned long long)mono_f32(bv) << 32)
                         | (uint32_t)(GRID - 1 - j);
      cprob[wv * NP + k] = pa;
      lm = fmaxf(fmaxf(sreg[0], sreg[1]), fmaxf(sreg[2], sreg[3]));
    }
  }
  __syncthreads();

  // --- phase 2: rank-merge. Lists are strictly descending, keys unique.
  //     rank = own position + sum over other lists of count-greater
  //     (6-probe branchless gallop per list). rank < 32 -> emit at that rank.
  if (tid < NCAND){
    const unsigned long long mykey = ckey[tid];
    const int myw = tid >> 5;
    int rank = tid & 31;               // position within own descending list
    for (int w = 0; w < NW; ++w){
      if (w == myw) continue;
      const unsigned long long* L = &ckey[w * NP];
      int c = 0;
      #pragma unroll
      for (int step = 16; step >= 1; step >>= 1){
        if (L[c + step - 1] > mykey) c += step;    // c stays <= 31
      }
      c += (L[c] > mykey) ? 1 : 0;                 // exact for count == 32
      rank += c;
    }
    if (rank < NP){
      const int j   = GRID - 1 - (int)(uint32_t)(mykey & 0xFFFFFFFFull);
      const int row = j >> 6, col = j & 63;
      int y0 = row * 32 - 48; y0 = y0 < 0 ? 0 : (y0 > 1920 ? 1920 : y0);
      int x0 = col * 32 - 48; x0 = x0 < 0 ? 0 : (x0 > 1920 ? 1920 : x0);
      ws_yx[b * NP + rank]    = make_int2(y0, x0);
      out_attn[b * NP + rank] = cprob[tid];
    }
  }
}

// Grid-stride: 3 float4s per thread; nontemporal stores (output never re-read).
__global__ __launch_bounds__(256) void gather_patches(const float* __restrict__ wsi,
                                                      const int2* __restrict__ ws_yx,
                                                      f32x4* __restrict__ out4){
  int t = blockIdx.x * 256 + threadIdx.x;
  #pragma unroll
  for (int it = 0; it < 3; ++it, t += GB * 256){
    const int lane = t & 31;          // float4 within the 128-float row
    const int row  = t >> 5;          // [0, 4*32*3*128)
    const int r    = row & 127;
    const int tmp  = row >> 7;        // b*96 + n*3 + c
    const int c    = tmp % 3;
    const int bn   = tmp / 3;         // b*32 + n
    const int b    = bn >> 5;
    const int2 yx  = ws_yx[bn];       // (y0, x0); x0 multiple of 16 -> float4 aligned
    const size_t off = ((size_t)((b * 3 + c) * HW + yx.x + r)) * HW + (size_t)yx.y;
    const f32x4 v = *reinterpret_cast<const f32x4*>(wsi + off + (size_t)lane * 4);
    __builtin_nontemporal_store(v, out4 + (size_t)row * 32 + lane);
  }
}
} // namespace

extern "C" void kernel_launch(void* const* d_in, const int* in_sizes, int n_in,
                              void* d_out, int out_size, void* d_ws, size_t ws_size,
                              hipStream_t stream) {
  const float* att = (const float*)d_in[2];
  const float* wsi = (const float*)d_in[3];
  float* out       = (float*)d_out;
  float* out_attn  = out + (size_t)B * NP * 3 * PATCH_ * PATCH_;  // 6,291,456
  int2*  ws_yx     = (int2*)d_ws;                                  // 4*32 pairs

  sample_topk<<<B, NT, 0, stream>>>(att, out_attn, ws_yx);

  gather_patches<<<GB, 256, 0, stream>>>(wsi, ws_yx, (f32x4*)out);
}